// Round 17
// baseline (194.389 us; speedup 1.0000x reference)
//
#include <hip/hip_runtime.h>
#include <stdint.h>
#include <math.h>

#define N 8192
#define BCAP 768
#define E 12            // E*64 == BCAP (slot coverage invariant)
#define OVF_MAX 4096

// ================= Sort stage (bitonic, exact argsort) =================
// key = (~monotone(score) << 32) | index; ascending sort == stable argsort
// of -scores. Network split: local k<=2048 (s1), k=4096 (s2), k=8192 (s3).

__global__ __launch_bounds__(1024) void k_sort1(const float* __restrict__ scores,
                                                uint64_t* __restrict__ keys,
                                                uint32_t* __restrict__ bcnt,
                                                uint32_t* __restrict__ ovfc) {
    __shared__ uint64_t sk[2048];
    int b = blockIdx.x, t = threadIdx.x;
    int base = b * 2048;
    if (b == 0) {               // zero bucket counters before k_mask
        if (t < 128) bcnt[t] = 0;
        if (t == 128) *ovfc = 0;
    }
    for (int e = 0; e < 2; ++e) {
        int li = t + e * 1024;
        int i = base + li;
        uint32_t sb = __float_as_uint(scores[i]);
        sb = (sb & 0x80000000u) ? ~sb : (sb | 0x80000000u);
        sk[li] = ((uint64_t)(~sb) << 32) | (uint32_t)i;
    }
    __syncthreads();
    for (int k = 2; k <= 2048; k <<= 1) {
        for (int j = k >> 1; j > 0; j >>= 1) {
            for (int e = 0; e < 2; ++e) {
                int li = t + e * 1024;
                int lixj = li ^ j;
                if (lixj > li) {
                    int gi = base + li;
                    bool up = ((gi & k) == 0);
                    uint64_t a = sk[li], c = sk[lixj];
                    if ((a > c) == up) { sk[li] = c; sk[lixj] = a; }
                }
            }
            __syncthreads();
        }
    }
    for (int e = 0; e < 2; ++e) { int li = t + e * 1024; keys[base + li] = sk[li]; }
}

// k=4096: cross pass j=2048 read from global (element-wise), then local j<=1024.
__global__ __launch_bounds__(1024) void k_sort2(const uint64_t* __restrict__ keys,
                                                uint64_t* __restrict__ keys2) {
    __shared__ uint64_t sk[2048];
    int b = blockIdx.x, t = threadIdx.x;
    int base = b * 2048;
    for (int e = 0; e < 2; ++e) {
        int li = t + e * 1024;
        int i = base + li;
        uint64_t a = keys[i], c = keys[i ^ 2048];
        bool up = ((i & 4096) == 0);
        bool lowpos = ((i & 2048) == 0);
        uint64_t mn = a < c ? a : c, mx = a < c ? c : a;
        sk[li] = (up == lowpos) ? mn : mx;
    }
    __syncthreads();
    for (int j = 1024; j > 0; j >>= 1) {
        for (int e = 0; e < 2; ++e) {
            int li = t + e * 1024;
            int lixj = li ^ j;
            if (lixj > li) {
                int gi = base + li;
                bool up = ((gi & 4096) == 0);
                uint64_t a = sk[li], c = sk[lixj];
                if ((a > c) == up) { sk[li] = c; sk[lixj] = a; }
            }
        }
        __syncthreads();
    }
    for (int e = 0; e < 2; ++e) { int li = t + e * 1024; keys2[base + li] = sk[li]; }
}

// k=8192 (up=true everywhere): cross passes j=4096,2048 from global, local
// j<=1024, then fused gather of boxes/scores into sorted order.
__global__ __launch_bounds__(1024) void k_sort3(const uint64_t* __restrict__ keys2,
                                                const float4* __restrict__ boxes,
                                                const float* __restrict__ scores,
                                                float4* __restrict__ bs,
                                                float* __restrict__ ss) {
    __shared__ uint64_t sk[2048];
    int b = blockIdx.x, t = threadIdx.x;
    int base = b * 2048;
    for (int e = 0; e < 2; ++e) {
        int li = t + e * 1024;
        int i = base + li;
        uint64_t a0 = keys2[i], a1 = keys2[i ^ 4096];
        bool low0 = ((i & 4096) == 0);
        uint64_t v = low0 ? (a0 < a1 ? a0 : a1) : (a0 < a1 ? a1 : a0);
        int q = i ^ 2048;
        uint64_t b0 = keys2[q], b1 = keys2[q ^ 4096];
        bool lowq = ((q & 4096) == 0);
        uint64_t vq = lowq ? (b0 < b1 ? b0 : b1) : (b0 < b1 ? b1 : b0);
        bool low2 = ((i & 2048) == 0);
        sk[li] = low2 ? (v < vq ? v : vq) : (v < vq ? vq : v);
    }
    __syncthreads();
    for (int j = 1024; j > 0; j >>= 1) {
        for (int e = 0; e < 2; ++e) {
            int li = t + e * 1024;
            int lixj = li ^ j;
            if (lixj > li) {
                uint64_t a = sk[li], c = sk[lixj];
                if (a > c) { sk[li] = c; sk[lixj] = a; }   // up = true
            }
        }
        __syncthreads();
    }
    for (int e = 0; e < 2; ++e) {
        int li = t + e * 1024;
        int gi = base + li;
        uint32_t idx = (uint32_t)sk[li];
        bs[gi] = boxes[idx];
        ss[gi] = scores[idx];
    }
}

// ---------------- Suppression bitmask -> word-bucketed sparse ----------------
// One wave per upper-triangle (R, word) tile; 8256 tiles = 2064 blocks x 4
// waves, perfectly balanced, zero barriers. word==R -> diag[row]; nonzero
// off-diagonal ballots appended to bucket[word] = {val, row}; entries beyond
// BCAP go to the exact global overflow list.
__global__ __launch_bounds__(256) void k_mask(const float4* __restrict__ bs,
                                              ulonglong2* __restrict__ bkt,
                                              uint32_t* __restrict__ bcnt,
                                              uint64_t* __restrict__ diag,
                                              ulonglong2* __restrict__ ovf,
                                              uint32_t* __restrict__ ovfc) {
    __shared__ float4 rb[4][64];
    __shared__ float  ra[4][64];
    int t = threadIdx.x;
    int lane = t & 63;
    int wv = t >> 6;
    int tile = blockIdx.x * 4 + wv;          // 0..8255

    // decode tile -> (R, word): off(R) = 128R - R(R-1)/2, word >= R
    int R = (int)((257.0 - sqrt(66049.0 - 8.0 * (double)tile)) * 0.5);
    while (128 * (R + 1) - ((R + 1) * R) / 2 <= tile) ++R;   // safety correction
    while (128 * R - (R * (R - 1)) / 2 > tile) --R;
    int word = R + tile - (128 * R - (R * (R - 1)) / 2);

    {   // stage this wave's 64 row boxes (wave-private LDS, no barrier needed)
        float4 b = bs[R * 64 + lane];
        rb[wv][lane] = b;
        ra[wv][lane] = ((b.z - b.x) + 1.0f) * ((b.w - b.y) + 1.0f);
    }
    int col = word * 64 + lane;
    float4 cb = bs[col];
    float ca = ((cb.z - cb.x) + 1.0f) * ((cb.w - cb.y) + 1.0f);

    for (int r = 0; r < 64; ++r) {
        int row = R * 64 + r;
        float4 rbv = rb[wv][r];
        float ix1 = fmaxf(rbv.x, cb.x);
        float iy1 = fmaxf(rbv.y, cb.y);
        float ix2 = fminf(rbv.z, cb.z);
        float iy2 = fminf(rbv.w, cb.w);
        float iw = fmaxf((ix2 - ix1) + 1.0f, 0.0f);
        float ih = fmaxf((iy2 - iy1) + 1.0f, 0.0f);
        float inter = iw * ih;
        float uni = (ra[wv][r] + ca) - inter;   // matches ref order
        float iou = inter / uni;                // IEEE div, matches numpy ref
        bool pred = (iou > 0.5f) && (col > row);
        uint64_t bal = __ballot(pred);
        if (lane == 0) {
            if (word == R) {
                diag[row] = bal;                 // intra-chunk word (all rows hit)
            } else if (bal) {
                uint32_t pos = atomicAdd(&bcnt[word], 1u);
                if (pos < BCAP) {
                    ulonglong2 v;
                    v.x = bal; v.y = (unsigned long long)(uint32_t)row;
                    bkt[(size_t)word * BCAP + pos] = v;
                } else {
                    uint32_t op = atomicAdd(ovfc, 1u);
                    if (op < OVF_MAX) {
                        ulonglong2 v;
                        v.x = bal;
                        v.y = (unsigned long long)(uint32_t)word |
                              ((unsigned long long)(uint32_t)row << 32);
                        ovf[op] = v;
                    }
                }
            }
        }
    }
}

// ---------------- Bucketed single-wave greedy scan ----------------
// 64 threads, zero barriers, NO LDS atomics. Per chunk c: remv word = OR of
// bucket-c entries whose source row (always in an earlier chunk) is kept,
// then the sparse diag recurrence. Entries/diag depth-2 register prefetch;
// counts depth-4. All readlane/readfirstlane results pass through explicit
// uint32_t locals (R8's failure was sign-extension of the int builtin).
__global__ __launch_bounds__(64, 1) void k_scan(const ulonglong2* __restrict__ bkt,
                                                const uint32_t* __restrict__ bcnt,
                                                const uint64_t* __restrict__ diag,
                                                const ulonglong2* __restrict__ ovf,
                                                const uint32_t* __restrict__ ovfc,
                                                uint64_t* __restrict__ keepw) {
    __shared__ uint64_t sh_remv[128];   // suppressed-word per completed chunk
    const int lane = threadIdx.x;
    const int novf = min((int)*ovfc, OVF_MAX);

    ulonglong2 EA[E], EB[E];
    uint64_t dA = diag[lane];           // chunk 0 diag
    uint64_t dB = diag[64 + lane];      // chunk 1 diag
    uint32_t c0 = bcnt[0], c1 = bcnt[1], c2 = bcnt[2], c3 = bcnt[3];
#pragma unroll
    for (int e = 0; e < E; ++e) {       // bucket 0 is empty; gated at consume
        EA[e] = bkt[lane + e * 64];
        EB[e] = bkt[(size_t)BCAP + lane + e * 64];
    }

#define RFL(x) __builtin_amdgcn_readfirstlane(x)
#define RL(x, i) __builtin_amdgcn_readlane(x, i)

#define PROCESS(C_, CUR, DC, CCUR, CNX2)                                       \
    {                                                                          \
        const int c_ = (C_);                                                   \
        uint32_t cnt_c = (uint32_t)RFL(CCUR);                                  \
        uint64_t d_cur = DC;                                                   \
        /* ensure prior chunk's sh_remv write retired before filter reads */   \
        asm volatile("s_waitcnt lgkmcnt(0)" ::: "memory");                     \
        uint64_t part = 0;                                                     \
        _Pragma("unroll")                                                      \
        for (int e = 0; e < E; ++e) {   /* keep-filter + partial OR */         \
            int slot = lane + e * 64;                                          \
            if ((uint32_t)slot < cnt_c) {                                      \
                int row = (int)(uint32_t)CUR[e].y;                             \
                uint64_t kw = sh_remv[row >> 6];                               \
                if (!((kw >> (row & 63)) & 1ull)) part |= CUR[e].x;            \
            }                                                                  \
        }                                                                      \
        if (cnt_c > (uint32_t)BCAP) {   /* exact overflow completion (rare) */ \
            for (int i = lane; i < novf; i += 64) {                            \
                ulonglong2 en = ovf[i];                                        \
                if ((int)(uint32_t)en.y == c_) {                               \
                    int row = (int)(en.y >> 32);                               \
                    uint64_t kw = sh_remv[row >> 6];                           \
                    if (!((kw >> (row & 63)) & 1ull)) part |= en.x;            \
                }                                                              \
            }                                                                  \
        }                                                                      \
        /* refills: counts 4 ahead, diag/entries 2 ahead (gated by count) */   \
        if (c_ + 4 < 128) CCUR = bcnt[c_ + 4];                                 \
        if (c_ + 2 < 128) {                                                    \
            DC = diag[(size_t)(c_ + 2) * 64 + lane];                           \
            uint32_t cn2 = (uint32_t)RFL(CNX2);                                \
            const ulonglong2* bp = bkt + (size_t)(c_ + 2) * BCAP;              \
            _Pragma("unroll")                                                  \
            for (int e = 0; e < E; ++e)                                        \
                if ((uint32_t)(e * 64) < cn2) CUR[e] = bp[lane + e * 64];      \
        }                                                                      \
        __builtin_amdgcn_sched_barrier(0);                                     \
        /* cross-lane OR-reduce of part (butterfly, u32 halves) */             \
        uint32_t plo = (uint32_t)part, phi = (uint32_t)(part >> 32);           \
        _Pragma("unroll")                                                      \
        for (int off = 1; off < 64; off <<= 1) {                               \
            plo |= (uint32_t)__shfl_xor((int)plo, off, 64);                    \
            phi |= (uint32_t)__shfl_xor((int)phi, off, 64);                    \
        }                                                                      \
        uint32_t wl = (uint32_t)RFL(plo);   /* explicit u32: no sext */        \
        uint32_t wh = (uint32_t)RFL(phi);                                      \
        uint64_t w_ = ((uint64_t)wh << 32) | wl;                               \
        /* sparse intra-chunk serial recurrence */                             \
        uint64_t bz = __ballot(d_cur != 0);                                    \
        uint32_t nl = (uint32_t)RFL((uint32_t)bz);                             \
        uint32_t nh = (uint32_t)RFL((uint32_t)(bz >> 32));                     \
        uint64_t nz = ((uint64_t)nh << 32) | nl;                               \
        uint32_t ml = (uint32_t)d_cur, mh = (uint32_t)(d_cur >> 32);           \
        while (nz) {                                                           \
            int i = (int)__builtin_ctzll(nz);                                  \
            nz &= nz - 1;                                                      \
            if (!((w_ >> i) & 1ull)) {                                         \
                uint32_t p0 = (uint32_t)RL(ml, i);                             \
                uint32_t p1 = (uint32_t)RL(mh, i);                             \
                w_ |= ((uint64_t)p1 << 32) | p0;                               \
            }                                                                  \
        }                                                                      \
        if (lane == 0) sh_remv[c_] = w_;                                       \
    }

    for (int cc = 0; cc < 128; cc += 4) {
        PROCESS(cc + 0, EA, dA, c0, c2)
        PROCESS(cc + 1, EB, dB, c1, c3)
        PROCESS(cc + 2, EA, dA, c2, c0)
        PROCESS(cc + 3, EB, dB, c3, c1)
    }
#undef PROCESS
#undef RFL
#undef RL

    // single coalesced keep write-out
    asm volatile("s_waitcnt lgkmcnt(0)" ::: "memory");
    keepw[lane] = ~sh_remv[lane];
    keepw[64 + lane] = ~sh_remv[64 + lane];
}

// ---------------- Masked outputs ----------------
__global__ void k_out(const float4* __restrict__ bs, const float* __restrict__ ss,
                      const uint64_t* __restrict__ keepw, float* __restrict__ out) {
    int i = blockIdx.x * blockDim.x + threadIdx.x;
    uint64_t wv = keepw[i >> 6];
    float m = ((wv >> (i & 63)) & 1ull) ? 1.0f : 0.0f;
    float4 b = bs[i];
    float4 ob;
    ob.x = b.x * m; ob.y = b.y * m; ob.z = b.z * m; ob.w = b.w * m;
    ((float4*)out)[i] = ob;
    out[4 * N + i] = ss[i] * m;
    out[5 * N + i] = m;
}

extern "C" void kernel_launch(void* const* d_in, const int* in_sizes, int n_in,
                              void* d_out, int out_size, void* d_ws, size_t ws_size,
                              hipStream_t stream) {
    const float* boxes  = (const float*)d_in[0];   // 8192 x 4 f32
    const float* scores = (const float*)d_in[1];   // 8192 f32

    char* ws = (char*)d_ws;
    float4*     bs    = (float4*)(ws + 0);          // 131072 B
    float*      ss    = (float*)(ws + 131072);      //  32768 B
    uint64_t*   keepw = (uint64_t*)(ws + 163840);   //   1024 B
    uint32_t*   bcnt  = (uint32_t*)(ws + 164864);   //    512 B (128 u32)
    uint32_t*   ovfc  = (uint32_t*)(ws + 165376);   //    512 B (padded)
    ulonglong2* ovf   = (ulonglong2*)(ws + 165888); //  65536 B (4096 x 16)
    uint64_t*   diag  = (uint64_t*)(ws + 231424);   //  65536 B (8192 u64)
    uint64_t*   keys  = (uint64_t*)(ws + 296960);   //  65536 B
    uint64_t*   keys2 = (uint64_t*)(ws + 362496);   //  65536 B
    ulonglong2* bkt   = (ulonglong2*)(ws + 524288); // 1572864 B (128 x 768 x 16)

    k_sort1<<<4, 1024, 0, stream>>>(scores, keys, bcnt, ovfc);
    k_sort2<<<4, 1024, 0, stream>>>(keys, keys2);
    k_sort3<<<4, 1024, 0, stream>>>(keys2, (const float4*)boxes, scores, bs, ss);
    k_mask <<<2064, 256, 0, stream>>>(bs, bkt, bcnt, diag, ovf, ovfc);
    k_scan <<<1, 64, 0, stream>>>(bkt, bcnt, diag, ovf, ovfc, keepw);
    k_out  <<<N / 256, 256, 0, stream>>>(bs, ss, keepw, (float*)d_out);
}